// Round 1
// baseline (60.355 us; speedup 1.0000x reference)
//
#include <hip/hip_runtime.h>
#include <math.h>

// ConfidenceCVXSelector: the reference's 4096x4096 eigh collapses analytically.
// A = fn fn^T is rank-2 (fn is Nx2, unit rows). With G = D^{-1/2} fn,
// S = D^{-1/2} A D^{-1/2} = G G^T has nonzero eigenpairs given by the 2x2
// Gram C = G^T G; lambda1 = 1 exactly (Perron, eigvec D^{1/2} 1), and the
// Fiedler vector of Ln ~= I - S is G u / ||G u|| with C u = lambda_min(C) u.
// Row sums: d_i = c_i*Sum(c) + s_i*Sum(s). Everything is O(N), one block.

constexpr int N  = 4096;
constexpr int NT = 1024;       // 16 waves
constexpr int PT = N / NT;     // 4 elements per thread
constexpr int NW = NT / 64;    // 16

__device__ __forceinline__ void block_reduce_sum(const double* vals, int m,
                                                 double* scr, double* outv) {
    const int lane = threadIdx.x & 63;
    const int wave = threadIdx.x >> 6;
    for (int j = 0; j < m; ++j) {
        double v = vals[j];
        #pragma unroll
        for (int off = 32; off > 0; off >>= 1) v += __shfl_down(v, off, 64);
        if (lane == 0) scr[j * NW + wave] = v;
    }
    __syncthreads();
    if (wave == 0) {
        for (int j = 0; j < m; ++j) {
            double v = (lane < NW) ? scr[j * NW + lane] : 0.0;
            #pragma unroll
            for (int off = 8; off > 0; off >>= 1) v += __shfl_down(v, off, 64);
            if (lane == 0) outv[j] = v;
        }
    }
    __syncthreads();
}

__global__ __launch_bounds__(NT) void spectral_kernel(const float* __restrict__ logits,
                                                      float* __restrict__ out) {
    __shared__ double s_scr[NW * 3];
    __shared__ double s_bc[4];
    __shared__ unsigned long long s_key[NW];
    __shared__ float s_mm[NW * 2];
    __shared__ float s_sign;

    const int tid  = threadIdx.x;
    const int lane = tid & 63;
    const int wave = tid >> 6;

    float c[PT], s[PT], dis[PT];

    // ---- phase A: per-pixel normalized features; reduce Sc, Ss ----
    double acc[3];
    acc[0] = 0.0; acc[1] = 0.0;
    #pragma unroll
    for (int k = 0; k < PT; ++k) {
        const int i = tid + k * NT;                 // coalesced
        float x  = logits[i];
        float p  = 1.0f / (1.0f + expf(-x));
        float mc = fmaxf(p, 1.0f - p);
        float v  = (1.0f - mc) / (mc + 1e-10f);
        float nr = fmaxf(sqrtf(mc * mc + v * v), 1e-12f);
        c[k] = mc / nr;
        s[k] = v / nr;
        acc[0] += (double)c[k];
        acc[1] += (double)s[k];
    }
    block_reduce_sum(acc, 2, s_scr, s_bc);
    const double Sc = s_bc[0];
    const double Ss = s_bc[1];

    // ---- phase B: d_i, dis_i; reduce 2x2 Gram C of G = D^{-1/2} fn ----
    acc[0] = 0.0; acc[1] = 0.0; acc[2] = 0.0;
    #pragma unroll
    for (int k = 0; k < PT; ++k) {
        double d  = (double)c[k] * Sc + (double)s[k] * Ss;
        double di = 1.0 / (sqrt(d) + 1e-10);
        dis[k] = (float)di;
        double gc = di * (double)c[k];
        double gs = di * (double)s[k];
        acc[0] += gc * gc;   // C11
        acc[1] += gc * gs;   // C12
        acc[2] += gs * gs;   // C22
    }
    block_reduce_sum(acc, 3, s_scr, s_bc);
    const double C11 = s_bc[0], C12 = s_bc[1], C22 = s_bc[2];

    // ---- 2x2 eigensolve (every thread, redundantly & deterministically) ----
    double tr   = C11 + C22;
    double df   = C11 - C22;
    double disc = sqrt(df * df + 4.0 * C12 * C12);
    double lmin = 0.5 * (tr - disc);                  // = lambda2 of S
    // eigenvector for lmin: pick the better-conditioned formula
    double ux1 = C12,        uy1 = lmin - C11;
    double ux2 = lmin - C22, uy2 = C12;
    double n1 = ux1 * ux1 + uy1 * uy1;
    double n2 = ux2 * ux2 + uy2 * uy2;
    double ux, uy, nn;
    if (n1 >= n2) { ux = ux1; uy = uy1; nn = n1; }
    else          { ux = ux2; uy = uy2; nn = n2; }
    double inv = 1.0 / sqrt(nn > 1e-300 ? nn : 1e-300);
    ux *= inv; uy *= inv;
    // ||G u||^2 = u^T C u = lmin  =>  scale to unit eigenvector
    double sfac = 1.0 / sqrt(lmin > 1e-300 ? lmin : 1e-300);

    // ---- phase C: f_i = dis_i (c_i ux + s_i uy) * sfac; min/max/argmax|f| ----
    float fl[PT];
    float vmin = 3.402823466e38f, vmax = -3.402823466e38f;
    unsigned long long key = 0ULL;
    #pragma unroll
    for (int k = 0; k < PT; ++k) {
        const unsigned i = (unsigned)(tid + k * NT);
        double fv = (double)dis[k] * ((double)c[k] * ux + (double)s[k] * uy) * sfac;
        float f = (float)fv;
        fl[k] = f;
        vmin = fminf(vmin, f);
        vmax = fmaxf(vmax, f);
        unsigned af = __float_as_uint(fabsf(f));    // monotone for non-negative floats
        unsigned long long kk =
            ((unsigned long long)af << 32) | (unsigned long long)(0xFFFFFFFFu - i);
        key = (kk > key) ? kk : key;                // ties -> smallest index (argmax semantics)
    }
    #pragma unroll
    for (int off = 32; off > 0; off >>= 1) {
        vmin = fminf(vmin, __shfl_down(vmin, off, 64));
        vmax = fmaxf(vmax, __shfl_down(vmax, off, 64));
        unsigned long long ok = __shfl_down(key, off, 64);
        key = (ok > key) ? ok : key;
    }
    if (lane == 0) { s_mm[wave] = vmin; s_mm[NW + wave] = vmax; s_key[wave] = key; }
    __syncthreads();
    if (wave == 0) {
        vmin = (lane < NW) ? s_mm[lane]      :  3.402823466e38f;
        vmax = (lane < NW) ? s_mm[NW + lane] : -3.402823466e38f;
        key  = (lane < NW) ? s_key[lane]     : 0ULL;
        #pragma unroll
        for (int off = 8; off > 0; off >>= 1) {
            vmin = fminf(vmin, __shfl_down(vmin, off, 64));
            vmax = fmaxf(vmax, __shfl_down(vmax, off, 64));
            unsigned long long ok = __shfl_down(key, off, 64);
            key = (ok > key) ? ok : key;
        }
        if (lane == 0) { s_mm[0] = vmin; s_mm[1] = vmax; s_key[0] = key; }
    }
    __syncthreads();
    vmin = s_mm[0]; vmax = s_mm[1]; key = s_key[0];
    const unsigned widx = 0xFFFFFFFFu - (unsigned)(key & 0xFFFFFFFFULL);

    // winner publishes sign(f[argmax|f|]); ref uses (f[idx] >= 0) ? +1 : -1
    #pragma unroll
    for (int k = 0; k < PT; ++k) {
        const unsigned i = (unsigned)(tid + k * NT);
        if (i == widx) s_sign = (fl[k] >= 0.0f) ? 1.0f : -1.0f;
    }
    __syncthreads();
    const float sgn  = s_sign;
    const float gmin = (sgn > 0.0f) ? vmin : -vmax;
    const float gmax = (sgn > 0.0f) ? vmax : -vmin;
    const float invr = 1.0f / (gmax - gmin + 1e-10f);

    #pragma unroll
    for (int k = 0; k < PT; ++k) {
        const int i = tid + k * NT;
        out[i] = (sgn * fl[k] - gmin) * invr;
    }
}

extern "C" void kernel_launch(void* const* d_in, const int* in_sizes, int n_in,
                              void* d_out, int out_size, void* d_ws, size_t ws_size,
                              hipStream_t stream) {
    const float* logits = (const float*)d_in[0];
    float* out = (float*)d_out;
    spectral_kernel<<<dim3(1), dim3(NT), 0, stream>>>(logits, out);
}

// Round 2
// 59.253 us; speedup vs baseline: 1.0186x; 1.0186x over previous
//
#include <hip/hip_runtime.h>
#include <math.h>

// ConfidenceCVXSelector: the reference's 4096x4096 eigh collapses analytically.
// A = fn fn^T is rank-2 (fn is Nx2, unit rows). With G = D^{-1/2} fn,
// S = D^{-1/2} A D^{-1/2} = G G^T has nonzero eigenpairs given by the 2x2
// Gram C = G^T G; lambda1 = 1 exactly (Perron, eigvec D^{1/2} 1), and the
// Fiedler vector of Ln ~= I - S is G u with C u = lambda_min(C) u.
// Row sums closed-form: d_i = c_i*Sum(c) + s_i*Sum(s). Everything O(N).
//
// R1: all per-element math in f32 (f64 div/sqrt sequences were the single-CU
// bottleneck); 2x2 eigensolve kept in f64 (O(1) cost). Sign-fix folded into
// the argmax key (|f|<<33 | inv_idx<<1 | signbit) - one less barrier, exact
// first-index tie-break preserved. float4 I/O.

constexpr int N  = 4096;
constexpr int NT = 1024;       // 16 waves, one block (one CU)
constexpr int PT = N / NT;     // 4 elements per thread
constexpr int NW = NT / 64;    // 16 waves

__device__ __forceinline__ void block_reduce_sum_f(const float* vals, int m,
                                                   float* scr, float* outv) {
    const int lane = threadIdx.x & 63;
    const int wave = threadIdx.x >> 6;
    for (int j = 0; j < m; ++j) {
        float v = vals[j];
        #pragma unroll
        for (int off = 32; off > 0; off >>= 1) v += __shfl_down(v, off, 64);
        if (lane == 0) scr[j * NW + wave] = v;
    }
    __syncthreads();
    if (wave == 0) {
        for (int j = 0; j < m; ++j) {
            float v = (lane < NW) ? scr[j * NW + lane] : 0.0f;
            #pragma unroll
            for (int off = 8; off > 0; off >>= 1) v += __shfl_down(v, off, 64);
            if (lane == 0) outv[j] = v;
        }
    }
    __syncthreads();
}

__global__ __launch_bounds__(NT) void spectral_kernel(const float4* __restrict__ logits4,
                                                      float4* __restrict__ out4) {
    __shared__ float s_scr[NW * 3];
    __shared__ float s_bc[4];
    __shared__ unsigned long long s_key[NW];
    __shared__ float s_mm[NW * 2];

    const int tid  = threadIdx.x;
    const int lane = tid & 63;
    const int wave = tid >> 6;

    float c[PT], s[PT], dis[PT];

    // ---- phase A: normalized features; reduce Sc, Ss ----
    const float4 x4 = logits4[tid];
    const float xs[PT] = {x4.x, x4.y, x4.z, x4.w};
    float acc[3];
    acc[0] = 0.0f; acc[1] = 0.0f;
    #pragma unroll
    for (int k = 0; k < PT; ++k) {
        float x  = xs[k];
        float p  = 1.0f / (1.0f + __expf(-x));
        float mc = fmaxf(p, 1.0f - p);
        float v  = (1.0f - mc) / (mc + 1e-10f);
        float nr = fmaxf(sqrtf(mc * mc + v * v), 1e-12f);
        c[k] = mc / nr;
        s[k] = v / nr;
        acc[0] += c[k];
        acc[1] += s[k];
    }
    block_reduce_sum_f(acc, 2, s_scr, s_bc);
    const float Sc = s_bc[0];
    const float Ss = s_bc[1];

    // ---- phase B: dis_i = 1/(sqrt(d_i)+1e-10); 2x2 Gram of G = D^{-1/2} fn ----
    acc[0] = 0.0f; acc[1] = 0.0f; acc[2] = 0.0f;
    #pragma unroll
    for (int k = 0; k < PT; ++k) {
        float d  = c[k] * Sc + s[k] * Ss;
        float di = 1.0f / (sqrtf(d) + 1e-10f);
        dis[k] = di;
        float gc = di * c[k];
        float gs = di * s[k];
        acc[0] += gc * gc;   // C11
        acc[1] += gc * gs;   // C12
        acc[2] += gs * gs;   // C22
    }
    block_reduce_sum_f(acc, 3, s_scr, s_bc);

    // ---- 2x2 eigensolve in double (O(1) per thread, redundant+deterministic) ----
    const double C11 = (double)s_bc[0], C12 = (double)s_bc[1], C22 = (double)s_bc[2];
    double tr   = C11 + C22;
    double df   = C11 - C22;
    double disc = sqrt(df * df + 4.0 * C12 * C12);
    double lmin = 0.5 * (tr - disc);                  // = lambda2 of S
    double ux1 = C12,        uy1 = lmin - C11;
    double ux2 = lmin - C22, uy2 = C12;
    double n1 = ux1 * ux1 + uy1 * uy1;
    double n2 = ux2 * ux2 + uy2 * uy2;
    double uxd, uyd, nn;
    if (n1 >= n2) { uxd = ux1; uyd = uy1; nn = n1; }
    else          { uxd = ux2; uyd = uy2; nn = n2; }
    double inv = 1.0 / sqrt(nn > 1e-300 ? nn : 1e-300);
    double sf  = inv / sqrt(lmin > 1e-300 ? lmin : 1e-300);  // unit-norm fied (scale-inv anyway)
    const float ux = (float)(uxd * sf);
    const float uy = (float)(uyd * sf);

    // ---- phase C: f_i = dis_i (c_i ux + s_i uy); min/max/argmax|f| with sign ----
    float fl[PT];
    float vmin = 3.402823466e38f, vmax = -3.402823466e38f;
    unsigned long long key = 0ULL;
    #pragma unroll
    for (int k = 0; k < PT; ++k) {
        const unsigned i = (unsigned)(tid * PT + k);
        float f = dis[k] * (c[k] * ux + s[k] * uy);
        fl[k] = f;
        vmin = fminf(vmin, f);
        vmax = fmaxf(vmax, f);
        unsigned af = __float_as_uint(fabsf(f));    // monotone for non-negative floats
        // key: |f| (31b) << 33 | inv_idx (32b) << 1 | signbit(f>=0)
        unsigned long long kk = ((unsigned long long)af << 33)
                              | ((unsigned long long)(0xFFFFFFFFu - i) << 1)
                              | (unsigned long long)(f >= 0.0f ? 1u : 0u);
        key = (kk > key) ? kk : key;                // ties -> smallest index (np.argmax)
    }
    #pragma unroll
    for (int off = 32; off > 0; off >>= 1) {
        vmin = fminf(vmin, __shfl_down(vmin, off, 64));
        vmax = fmaxf(vmax, __shfl_down(vmax, off, 64));
        unsigned long long ok = __shfl_down(key, off, 64);
        key = (ok > key) ? ok : key;
    }
    if (lane == 0) { s_mm[wave] = vmin; s_mm[NW + wave] = vmax; s_key[wave] = key; }
    __syncthreads();
    if (wave == 0) {
        vmin = (lane < NW) ? s_mm[lane]      :  3.402823466e38f;
        vmax = (lane < NW) ? s_mm[NW + lane] : -3.402823466e38f;
        key  = (lane < NW) ? s_key[lane]     : 0ULL;
        #pragma unroll
        for (int off = 8; off > 0; off >>= 1) {
            vmin = fminf(vmin, __shfl_down(vmin, off, 64));
            vmax = fmaxf(vmax, __shfl_down(vmax, off, 64));
            unsigned long long ok = __shfl_down(key, off, 64);
            key = (ok > key) ? ok : key;
        }
        if (lane == 0) { s_mm[0] = vmin; s_mm[1] = vmax; s_key[0] = key; }
    }
    __syncthreads();
    vmin = s_mm[0]; vmax = s_mm[1];
    const float sgn  = (s_key[0] & 1ULL) ? 1.0f : -1.0f;
    const float gmin = (sgn > 0.0f) ? vmin : -vmax;
    const float gmax = (sgn > 0.0f) ? vmax : -vmin;
    const float invr = 1.0f / (gmax - gmin + 1e-10f);

    float4 o;
    o.x = (sgn * fl[0] - gmin) * invr;
    o.y = (sgn * fl[1] - gmin) * invr;
    o.z = (sgn * fl[2] - gmin) * invr;
    o.w = (sgn * fl[3] - gmin) * invr;
    out4[tid] = o;
}

extern "C" void kernel_launch(void* const* d_in, const int* in_sizes, int n_in,
                              void* d_out, int out_size, void* d_ws, size_t ws_size,
                              hipStream_t stream) {
    const float4* logits4 = (const float4*)d_in[0];
    float4* out4 = (float4*)d_out;
    spectral_kernel<<<dim3(1), dim3(NT), 0, stream>>>(logits4, out4);
}

// Round 3
// 57.465 us; speedup vs baseline: 1.0503x; 1.0311x over previous
//
#include <hip/hip_runtime.h>
#include <math.h>

// ConfidenceCVXSelector: the reference's 4096x4096 eigh collapses analytically.
// A = fn fn^T is rank-2 (fn is Nx2, unit rows). With G = D^{-1/2} fn,
// S = D^{-1/2} A D^{-1/2} = G G^T has nonzero eigenpairs given by the 2x2
// Gram C = G^T G; lambda1 = 1 exactly (Perron, eigvec D^{1/2} 1), and the
// Fiedler vector of Ln ~= I - S is G u with C u = lambda_min(C) u.
// Row sums closed-form: d_i = c_i*Sum(c) + s_i*Sum(s). Everything O(N).
//
// R2: latency-focused. 8 waves (512 thr, 8 elem/thr), each block reduction is
// ONE barrier (wave shuffle-reduce -> 8 LDS partials -> barrier -> every
// thread serially sums partials in fixed order, deterministic). 6 barriers -> 3.
// Total time is dominated by the harness's 256MB ws re-poison (~40us) +
// launch overhead; kernel itself is ~2us.

constexpr int N  = 4096;
constexpr int NT = 512;        // 8 waves, one block (one CU)
constexpr int PT = N / NT;     // 8 elements per thread
constexpr int NW = NT / 64;    // 8 waves

__global__ __launch_bounds__(NT) void spectral_kernel(const float4* __restrict__ logits4,
                                                      float4* __restrict__ out4) {
    __shared__ float s_scr[3 * NW];
    __shared__ float s_mm[2 * NW];
    __shared__ unsigned long long s_key[NW];

    const int tid  = threadIdx.x;
    const int lane = tid & 63;
    const int wave = tid >> 6;

    float c[PT], s[PT], dis[PT];

    // ---- phase A: normalized features; reduce Sc, Ss (1 barrier) ----
    const float4 xa = logits4[2 * tid];
    const float4 xb = logits4[2 * tid + 1];
    const float xs[PT] = {xa.x, xa.y, xa.z, xa.w, xb.x, xb.y, xb.z, xb.w};
    float a0 = 0.0f, a1 = 0.0f;
    #pragma unroll
    for (int k = 0; k < PT; ++k) {
        float x  = xs[k];
        float p  = 1.0f / (1.0f + __expf(-x));
        float mc = fmaxf(p, 1.0f - p);
        float v  = (1.0f - mc) / (mc + 1e-10f);
        float nr = fmaxf(sqrtf(mc * mc + v * v), 1e-12f);
        c[k] = mc / nr;
        s[k] = v / nr;
        a0 += c[k];
        a1 += s[k];
    }
    #pragma unroll
    for (int off = 32; off > 0; off >>= 1) {
        a0 += __shfl_down(a0, off, 64);
        a1 += __shfl_down(a1, off, 64);
    }
    if (lane == 0) { s_scr[wave] = a0; s_scr[NW + wave] = a1; }
    __syncthreads();
    float Sc = 0.0f, Ss = 0.0f;
    #pragma unroll
    for (int w = 0; w < NW; ++w) { Sc += s_scr[w]; Ss += s_scr[NW + w]; }

    // ---- phase B: dis_i; 2x2 Gram of G = D^{-1/2} fn (1 barrier) ----
    float b0 = 0.0f, b1 = 0.0f, b2 = 0.0f;
    #pragma unroll
    for (int k = 0; k < PT; ++k) {
        float d  = c[k] * Sc + s[k] * Ss;
        float di = 1.0f / (sqrtf(d) + 1e-10f);
        dis[k] = di;
        float gc = di * c[k];
        float gs = di * s[k];
        b0 += gc * gc;   // C11
        b1 += gc * gs;   // C12
        b2 += gs * gs;   // C22
    }
    #pragma unroll
    for (int off = 32; off > 0; off >>= 1) {
        b0 += __shfl_down(b0, off, 64);
        b1 += __shfl_down(b1, off, 64);
        b2 += __shfl_down(b2, off, 64);
    }
    __syncthreads();   // protect s_scr reuse (phase A reads done)
    if (lane == 0) { s_scr[wave] = b0; s_scr[NW + wave] = b1; s_scr[2 * NW + wave] = b2; }
    __syncthreads();
    float fC11 = 0.0f, fC12 = 0.0f, fC22 = 0.0f;
    #pragma unroll
    for (int w = 0; w < NW; ++w) {
        fC11 += s_scr[w];
        fC12 += s_scr[NW + w];
        fC22 += s_scr[2 * NW + w];
    }

    // ---- 2x2 eigensolve in double (O(1), redundant+deterministic) ----
    const double C11 = (double)fC11, C12 = (double)fC12, C22 = (double)fC22;
    double tr   = C11 + C22;
    double df   = C11 - C22;
    double disc = sqrt(df * df + 4.0 * C12 * C12);
    double lmin = 0.5 * (tr - disc);                  // = lambda2 of S
    double ux1 = C12,        uy1 = lmin - C11;
    double ux2 = lmin - C22, uy2 = C12;
    double n1 = ux1 * ux1 + uy1 * uy1;
    double n2 = ux2 * ux2 + uy2 * uy2;
    double uxd, uyd, nn;
    if (n1 >= n2) { uxd = ux1; uyd = uy1; nn = n1; }
    else          { uxd = ux2; uyd = uy2; nn = n2; }
    double inv = 1.0 / sqrt(nn > 1e-300 ? nn : 1e-300);
    double sf  = inv / sqrt(lmin > 1e-300 ? lmin : 1e-300);
    const float ux = (float)(uxd * sf);
    const float uy = (float)(uyd * sf);

    // ---- phase C: f_i; min/max/argmax|f| with sign folded in (1 barrier) ----
    float fl[PT];
    float vmin = 3.402823466e38f, vmax = -3.402823466e38f;
    unsigned long long key = 0ULL;
    #pragma unroll
    for (int k = 0; k < PT; ++k) {
        const unsigned i = (unsigned)(tid * PT + k);
        float f = dis[k] * (c[k] * ux + s[k] * uy);
        fl[k] = f;
        vmin = fminf(vmin, f);
        vmax = fmaxf(vmax, f);
        unsigned af = __float_as_uint(fabsf(f));    // monotone for non-negative floats
        // key: |f| (31b) << 33 | inv_idx (32b) << 1 | (f>=0)
        unsigned long long kk = ((unsigned long long)af << 33)
                              | ((unsigned long long)(0xFFFFFFFFu - i) << 1)
                              | (unsigned long long)(f >= 0.0f ? 1u : 0u);
        key = (kk > key) ? kk : key;                // ties -> smallest index (np.argmax)
    }
    #pragma unroll
    for (int off = 32; off > 0; off >>= 1) {
        vmin = fminf(vmin, __shfl_down(vmin, off, 64));
        vmax = fmaxf(vmax, __shfl_down(vmax, off, 64));
        unsigned long long ok = __shfl_down(key, off, 64);
        key = (ok > key) ? ok : key;
    }
    if (lane == 0) { s_mm[wave] = vmin; s_mm[NW + wave] = vmax; s_key[wave] = key; }
    __syncthreads();
    vmin = s_mm[0]; vmax = s_mm[NW]; key = s_key[0];
    #pragma unroll
    for (int w = 1; w < NW; ++w) {
        vmin = fminf(vmin, s_mm[w]);
        vmax = fmaxf(vmax, s_mm[NW + w]);
        unsigned long long ok = s_key[w];
        key = (ok > key) ? ok : key;
    }

    const float sgn  = (key & 1ULL) ? 1.0f : -1.0f;
    const float gmin = (sgn > 0.0f) ? vmin : -vmax;
    const float gmax = (sgn > 0.0f) ? vmax : -vmin;
    const float invr = 1.0f / (gmax - gmin + 1e-10f);

    float4 oa, ob;
    oa.x = (sgn * fl[0] - gmin) * invr;
    oa.y = (sgn * fl[1] - gmin) * invr;
    oa.z = (sgn * fl[2] - gmin) * invr;
    oa.w = (sgn * fl[3] - gmin) * invr;
    ob.x = (sgn * fl[4] - gmin) * invr;
    ob.y = (sgn * fl[5] - gmin) * invr;
    ob.z = (sgn * fl[6] - gmin) * invr;
    ob.w = (sgn * fl[7] - gmin) * invr;
    out4[2 * tid]     = oa;
    out4[2 * tid + 1] = ob;
}

extern "C" void kernel_launch(void* const* d_in, const int* in_sizes, int n_in,
                              void* d_out, int out_size, void* d_ws, size_t ws_size,
                              hipStream_t stream) {
    const float4* logits4 = (const float4*)d_in[0];
    float4* out4 = (float4*)d_out;
    spectral_kernel<<<dim3(1), dim3(NT), 0, stream>>>(logits4, out4);
}